// Round 9
// baseline (801.424 us; speedup 1.0000x reference)
//
#include <hip/hip_runtime.h>
#include <hip/hip_bf16.h>

typedef __attribute__((ext_vector_type(8))) short short8;
typedef __attribute__((ext_vector_type(4))) float f32x4;

#define THREADS 512
#define MFMA(a, b, c) __builtin_amdgcn_mfma_f32_16x16x32_bf16((a), (b), (c), 0, 0, 0)

static __device__ __forceinline__ unsigned short f2bf(float x) {
    __hip_bfloat16 h = __float2bfloat16(x);
    return __builtin_bit_cast(unsigned short, h);
}
static __device__ __forceinline__ unsigned pk2(float a, float b) {
    return (unsigned)f2bf(a) | ((unsigned)f2bf(b) << 16);
}
static __device__ __forceinline__ float bflo(unsigned u) {
    unsigned v = u << 16; return __builtin_bit_cast(float, v);
}
static __device__ __forceinline__ float bfhi(unsigned u) {
    unsigned v = u & 0xffff0000u; return __builtin_bit_cast(float, v);
}
static __device__ __forceinline__ float fast_tanh(float x) {
    float e = __builtin_amdgcn_exp2f(x * 2.885390081777927f);
    float r = __builtin_amdgcn_rcpf(e + 1.0f);
    return fmaf(-2.0f, r, 1.0f);
}
static __device__ __forceinline__ short8 cvt8(float4 a, float4 b) {
    short8 r;
    r[0] = (short)f2bf(a.x); r[1] = (short)f2bf(a.y);
    r[2] = (short)f2bf(a.z); r[3] = (short)f2bf(a.w);
    r[4] = (short)f2bf(b.x); r[5] = (short)f2bf(b.y);
    r[6] = (short)f2bf(b.z); r[7] = (short)f2bf(b.w);
    return r;
}

// Streamed-B GEMM: A bf16 frags in LDS (2 mt x 16 kt), B f32 rows read straight
// from d_in weights (L2-cacheable). NT 16-col tiles per wave. First NKT_S kt are
// streamed with a 1-deep register prefetch (fa/fb, fully unrolled -> static regs);
// optional 3-kt bf16 tail served from the LDS cache bc (Wh kt 13..15).
// B-frag mapping (round-1-verified): lane holds W[w*NT*16 + nt*16 + (l&15)][kt*32 + (l>>4)*8 + e]
template<int NT, int NKT_S, bool TAIL>
static __device__ __forceinline__ void gemm_f32B(
    const unsigned short* sfr, const float* __restrict__ Wsrc,
    const unsigned short* bc, f32x4 (&acc)[2][NT], const int w, const int l)
{
    const int q = l >> 4, c = l & 15;
    const float* bp = Wsrc + (size_t)(w * (NT * 16) + c) * 512 + q * 8;
    float4 fa[NT][2], fb[NT][2];
    #pragma unroll
    for (int nt = 0; nt < NT; ++nt) {
        fa[nt][0] = *(const float4*)(bp + nt * 8192);
        fa[nt][1] = *(const float4*)(bp + nt * 8192 + 4);
    }
    #pragma unroll
    for (int kt = 0; kt < NKT_S; ++kt) {
        if (kt + 1 < NKT_S) {
            #pragma unroll
            for (int nt = 0; nt < NT; ++nt) {
                fb[nt][0] = *(const float4*)(bp + nt * 8192 + (kt + 1) * 32);
                fb[nt][1] = *(const float4*)(bp + nt * 8192 + (kt + 1) * 32 + 4);
            }
        }
        short8 a0 = *(const short8*)(sfr + (kt * 64 + l) * 8);
        short8 a1 = *(const short8*)(sfr + ((16 + kt) * 64 + l) * 8);
        #pragma unroll
        for (int nt = 0; nt < NT; ++nt) {
            short8 b = cvt8(fa[nt][0], fa[nt][1]);
            acc[0][nt] = MFMA(a0, b, acc[0][nt]);
            acc[1][nt] = MFMA(a1, b, acc[1][nt]);
        }
        if (kt + 1 < NKT_S) {
            #pragma unroll
            for (int nt = 0; nt < NT; ++nt) { fa[nt][0] = fb[nt][0]; fa[nt][1] = fb[nt][1]; }
        }
    }
    if (TAIL) {
        #pragma unroll
        for (int ktL = 0; ktL < 3; ++ktL) {
            const int kt = 13 + ktL;
            short8 a0 = *(const short8*)(sfr + (kt * 64 + l) * 8);
            short8 a1 = *(const short8*)(sfr + ((16 + kt) * 64 + l) * 8);
            #pragma unroll
            for (int nt = 0; nt < NT; ++nt) {
                short8 b = *(const short8*)(bc + (size_t)((ktL * 32 + (w * NT + nt)) * 64 + l) * 8);
                acc[0][nt] = MFMA(a0, b, acc[0][nt]);
                acc[1][nt] = MFMA(a1, b, acc[1][nt]);
            }
        }
    }
}

__global__ __attribute__((amdgpu_flat_work_group_size(512, 512), amdgpu_waves_per_eu(2, 2)))
void toroidal(
    const float* __restrict__ x,
    const float* __restrict__ Wx_w, const float* __restrict__ wxb,
    const float* __restrict__ Wh_w, const float* __restrict__ whb,
    const float* __restrict__ Hd_w, const float* __restrict__ hdb,
    const float* __restrict__ gamma_p, const float* __restrict__ alphas,
    const int* __restrict__ steps_p,
    float* __restrict__ out)
{
    __shared__ __align__(16) unsigned short sfrag[16384];      // 32 KB A-frags [mt2][kt16][lane64][e8]
    __shared__ __align__(16) unsigned short bc[3 * 32 * 64 * 8]; // 96 KB Wh bf16 cache, kt 13..15

    const int tid = threadIdx.x;
    const int w = tid >> 6;          // wave: cols [w*64, w*64+64)
    const int l = tid & 63;
    const int q = l >> 4;
    const int c = l & 15;
    const int rbase = blockIdx.x * 32;

    const float gm = gamma_p[0];
    const float g1 = gm * alphas[0], g2 = gm * alphas[1], g3 = gm * alphas[2];
    const int nsteps = steps_p[0];

    float bsum[4];
    #pragma unroll
    for (int nt = 0; nt < 4; ++nt) {
        int col = w * 64 + nt * 16 + c;
        bsum[nt] = wxb[col] + whb[col];
    }
    const float hb0 = hdb[w * 32 + c], hb1 = hdb[w * 32 + 16 + c];

    // ---- one-time: fill LDS Wh cache (kt 13..15) from f32 source ----
    #pragma unroll
    for (int j = 0; j < 12; ++j) {
        int idx = tid + j * THREADS;            // [0, 6144)
        int lane = idx & 63;
        int ntg  = (idx >> 6) & 31;
        int ktL  = idx >> 11;                   // 0..2
        int col = ntg * 16 + (lane & 15);
        int k   = (13 + ktL) * 32 + (lane >> 4) * 8;
        const float* sp = Wh_w + (size_t)col * 512 + k;
        float4 a = *(const float4*)sp, b = *(const float4*)(sp + 4);
        short8 v = cvt8(a, b);
        *(short8*)&bc[(size_t)idx * 8] = v;
    }

    // ---- one-time: pack x tile (32 rows) into sfrag as bf16 A-frags (R1-verified) ----
    #pragma unroll
    for (int j = 0; j < 4; ++j) {
        int f = tid + j * THREADS;              // [0, 2048)
        int mt = f >> 10;
        int kt = (f >> 6) & 15;
        int lf = f & 63;
        int row = mt * 16 + (lf & 15);
        int k0  = kt * 32 + (lf >> 4) * 8;
        const float* sp = x + (size_t)(rbase + row) * 512 + k0;
        float4 a = *(const float4*)sp;
        float4 b = *(const float4*)(sp + 4);
        short8 v = cvt8(a, b);
        *(short8*)&sfrag[(size_t)f * 8] = v;
    }
    __syncthreads();

    // ---- xproj = x @ Wx^T (+ biases folded), B streamed f32 from d_in ----
    f32x4 acc[2][4];
    #pragma unroll
    for (int mt = 0; mt < 2; ++mt)
        #pragma unroll
        for (int nt = 0; nt < 4; ++nt)
            acc[mt][nt] = (f32x4){0.f, 0.f, 0.f, 0.f};
    gemm_f32B<4, 16, false>(sfrag, Wx_w, nullptr, acc, w, l);

    unsigned xpk[2][4][2];
    #pragma unroll
    for (int mt = 0; mt < 2; ++mt)
        #pragma unroll
        for (int nt = 0; nt < 4; ++nt) {
            float b = bsum[nt];
            xpk[mt][nt][0] = pk2(acc[mt][nt][0] + b, acc[mt][nt][1] + b);
            xpk[mt][nt][1] = pk2(acc[mt][nt][2] + b, acc[mt][nt][3] + b);
        }
    __syncthreads();   // xproj sfrag reads done before step-1 scatter overwrites

    // ---- state init ----
    float s[2][4][4];
    unsigned hh[3][2][4][2];
    #pragma unroll
    for (int mt = 0; mt < 2; ++mt)
        #pragma unroll
        for (int nt = 0; nt < 4; ++nt) {
            acc[mt][nt] = (f32x4){0.f, 0.f, 0.f, 0.f};
            #pragma unroll
            for (int i = 0; i < 4; ++i) s[mt][nt][i] = 0.f;
            #pragma unroll
            for (int a = 0; a < 3; ++a) { hh[a][mt][nt][0] = 0u; hh[a][mt][nt][1] = 0u; }
        }

    // per-thread scatter base (R1-verified C-frag -> A-frag mapping)
    const int tIdx = (w * 2048 + q * 64 + (l & 7) * 2 + (((l >> 3) & 1) << 8)) >> 1;

    // ---- recurrence: scatter(s_{t-1}) -> GEMM -> elementwise -> s_t ----
    for (int t = 0; t < nsteps; ++t) {
        #pragma unroll
        for (int mt = 0; mt < 2; ++mt)
            #pragma unroll
            for (int nt = 0; nt < 4; ++nt)
                #pragma unroll
                for (int i = 0; i < 4; ++i) {
                    const int off = (mt * 16384 + (nt >> 1) * 1024 + ((2 * nt) & 3) * 256 + i * 16) >> 1;
                    sfrag[tIdx + off] = f2bf(s[mt][nt][i]);
                }
        __syncthreads();

        gemm_f32B<4, 13, true>(sfrag, Wh_w, bc, acc, w, l);
        __syncthreads();   // all sfrag reads done before next-iter scatter

        // elementwise: pre = acc + xp + g·(a1 s-2 + a2 s-3 + a3 s-4); s = .5 s + .5 tanh(pre)
        #pragma unroll
        for (int mt = 0; mt < 2; ++mt)
            #pragma unroll
            for (int nt = 0; nt < 4; ++nt)
                #pragma unroll
                for (int p = 0; p < 2; ++p) {
                    unsigned u1 = hh[0][mt][nt][p];
                    unsigned u2 = hh[1][mt][nt][p];
                    unsigned u3 = hh[2][mt][nt][p];
                    unsigned ux = xpk[mt][nt][p];
                    float pre0 = acc[mt][nt][2 * p] + bflo(ux)
                               + g1 * bflo(u1) + g2 * bflo(u2) + g3 * bflo(u3);
                    float pre1 = acc[mt][nt][2 * p + 1] + bfhi(ux)
                               + g1 * bfhi(u1) + g2 * bfhi(u2) + g3 * bfhi(u3);
                    float so0 = s[mt][nt][2 * p], so1 = s[mt][nt][2 * p + 1];
                    s[mt][nt][2 * p]     = 0.5f * so0 + 0.5f * fast_tanh(pre0);
                    s[mt][nt][2 * p + 1] = 0.5f * so1 + 0.5f * fast_tanh(pre1);
                    hh[2][mt][nt][p] = u2;           // lag shift (R1-verified)
                    hh[1][mt][nt][p] = u1;
                    hh[0][mt][nt][p] = pk2(so0, so1);
                    acc[mt][nt][2 * p] = 0.f;
                    acc[mt][nt][2 * p + 1] = 0.f;    // reset for next GEMM
                }
    }

    // ---- head: out = s_final @ Head^T + Head_b (B streamed f32 from d_in) ----
    #pragma unroll
    for (int mt = 0; mt < 2; ++mt)
        #pragma unroll
        for (int nt = 0; nt < 4; ++nt)
            #pragma unroll
            for (int i = 0; i < 4; ++i) {
                const int off = (mt * 16384 + (nt >> 1) * 1024 + ((2 * nt) & 3) * 256 + i * 16) >> 1;
                sfrag[tIdx + off] = f2bf(s[mt][nt][i]);
            }
    __syncthreads();

    f32x4 acch[2][2];
    #pragma unroll
    for (int mt = 0; mt < 2; ++mt)
        #pragma unroll
        for (int nt = 0; nt < 2; ++nt)
            acch[mt][nt] = (f32x4){0.f, 0.f, 0.f, 0.f};
    gemm_f32B<2, 16, false>(sfrag, Hd_w, nullptr, acch, w, l);

    #pragma unroll
    for (int nt = 0; nt < 2; ++nt) {
        int col = w * 32 + nt * 16 + c;            // 8 waves x 32 = 256 cols
        float hb = nt ? hb1 : hb0;
        #pragma unroll
        for (int mt = 0; mt < 2; ++mt)
            #pragma unroll
            for (int i = 0; i < 4; ++i)
                out[(size_t)(rbase + mt * 16 + q * 4 + i) * 256 + col] = acch[mt][nt][i] + hb;
    }
}

extern "C" void kernel_launch(void* const* d_in, const int* in_sizes, int n_in,
                              void* d_out, int out_size, void* d_ws, size_t ws_size,
                              hipStream_t stream) {
    (void)n_in; (void)out_size; (void)d_ws; (void)ws_size;
    const float* x    = (const float*)d_in[0];
    const float* Wx_w = (const float*)d_in[1];
    const float* Wx_b = (const float*)d_in[2];
    const float* Wh_w = (const float*)d_in[3];
    const float* Wh_b = (const float*)d_in[4];
    const float* Hd_w = (const float*)d_in[5];
    const float* Hd_b = (const float*)d_in[6];
    const float* gma  = (const float*)d_in[7];
    const float* alp  = (const float*)d_in[8];
    const int*   stp  = (const int*)d_in[9];
    float* out = (float*)d_out;

    int batch = in_sizes[0] / 512;                 // 8192
    int nblk  = batch / 32;                        // 256 blocks, 1 per CU
    toroidal<<<nblk, THREADS, 0, stream>>>(x, Wx_w, Wx_b, Wh_w, Wh_b, Hd_w, Hd_b,
                                           gma, alp, stp, out);
}